// Round 3
// baseline (382.183 us; speedup 1.0000x reference)
//
#include <hip/hip_runtime.h>
#include <hip/hip_bf16.h>
#include <stdint.h>

#define B_ROWS 16384
#define D_IN   1200
#define D_PAD  1216      // 19 * 64
#define N_EXP  8
#define H_DIM  1024
#define R_CAP  4608      // fixed per-expert region (counts ~4096 +- 55; 9 sigma margin)
#define CAP    36864     // 8 * R_CAP
#define N_RT   288       // CAP / 128 row-tiles (36 per expert/XCD)
#define LN_EPS 1e-5f
#define GATE_EPS 1e-6f
#define CNT_STRIDE 16    // pad expert counters to separate 64B cache lines

// ---- workspace layout (bytes) ----
#define O_CNT    0           // 512 B
#define O_PROWC  512         // 36864 ints  -> 147968
#define O_PGATEC 147968      // 36864 floats -> 295424
#define O_XBF    295424      // 16385*1216*2 -> 40143744 (row 16384 = zeros)
#define O_W1T    40143744    // 8*1024*1216*2 -> 60066688
#define O_HBUF   60066688    // 36864*1024*2 -> 135564160 (~130 MB total)

#define GATING_BLOCKS (B_ROWS / 16)       // 1024 (4 rows/wave, 4 waves)
#define W1T_BLOCKS    (19 * 16 * 8)       // 2432  (64d x 64h tiles)
#define PREP_BLOCKS   (GATING_BLOCKS + 1 + W1T_BLOCKS)   // 3457

#define NT        (D_PAD / 32)            // 38 K-tiles

typedef short bf16x8 __attribute__((ext_vector_type(8)));
typedef short short8 __attribute__((ext_vector_type(8)));
typedef short short4v __attribute__((ext_vector_type(4)));
typedef float f32x4 __attribute__((ext_vector_type(4)));

__device__ __forceinline__ void load_lds16(const void* gptr, void* ldsptr) {
    __builtin_amdgcn_global_load_lds(
        (__attribute__((address_space(1))) void*)const_cast<void*>(gptr),
        (__attribute__((address_space(3))) void*)ldsptr, 16, 0, 0);
}

__device__ __forceinline__ short4v pack_bf16x4(float4 a) {
    union { short4v v; __hip_bfloat16 h[4]; } u;
    u.h[0] = __float2bfloat16(a.x); u.h[1] = __float2bfloat16(a.y);
    u.h[2] = __float2bfloat16(a.z); u.h[3] = __float2bfloat16(a.w);
    return u.v;
}

// ---------------- 1. prep: gating (blocks 0..1024) + W1 transpose (blocks 1025..) ----------------
// gating and w1t are independent; merging lets the BW-light transpose overlap the
// BW-heavy gating instead of serializing, and saves a launch gap.  (verified ~11us, R2)
__global__ __launch_bounds__(256) void prep_kernel(
    const float* __restrict__ x, const float* __restrict__ wg,
    int* __restrict__ cnt, int* __restrict__ pairRowC, float* __restrict__ pairGateC,
    __hip_bfloat16* __restrict__ xbf, float* __restrict__ y,
    const float* __restrict__ W1, __hip_bfloat16* __restrict__ w1t)
{
    __shared__ int lcnt[N_EXP];
    __shared__ int base[N_EXP];
    __shared__ float tile[2][32][33];
    int bx = blockIdx.x;
    int tid = threadIdx.x;

    if (bx > GATING_BLOCKS) {
        // ---- w1t part: W1 [E][D][H] fp32 -> w1t [E][H][D_PAD] bf16 ----
        int b = bx - GATING_BLOCKS - 1;        // [0, 2432)
        int d0 = (b % 19) * 64;
        int h0 = ((b / 19) % 16) * 64;
        int e = b / (19 * 16);
        const float* src = W1 + (long)e * D_IN * H_DIM;

        int hs = tid & 15;
        int dr = tid >> 4;
#pragma unroll
        for (int s = 0; s < 4; ++s) {
            int dl = dr + 16 * s;    // 0..63
            int d = d0 + dl;
            float4 v = (d < D_IN)
                ? ((const float4*)(src + (long)d * H_DIM + h0))[hs]
                : (float4){0.f, 0.f, 0.f, 0.f};
            int drl = dl & 31;
            int hl = hs * 4;
            int Th = hl >> 5;
            int hh = hl & 31;
            tile[Th][drl][hh + 0] = v.x;
            tile[Th][drl][hh + 1] = v.y;
            tile[Th][drl][hh + 2] = v.z;
            tile[Th][drl][hh + 3] = v.w;
            if (s == 1) {            // drain d-half 0
                __syncthreads();
                int T2 = tid >> 7, rr = tid & 127;
                int hl2 = rr >> 2, dseg = rr & 3;
                float f[8];
#pragma unroll
                for (int jj = 0; jj < 8; ++jj) f[jj] = tile[T2][dseg * 8 + jj][hl2];
                union { short8 v8; __hip_bfloat16 hh8[8]; } u;
#pragma unroll
                for (int jj = 0; jj < 8; ++jj) u.hh8[jj] = __float2bfloat16(f[jj]);
                int h = h0 + T2 * 32 + hl2;
                ((short8*)(w1t + (long)e * H_DIM * D_PAD + (long)h * D_PAD + d0))[dseg] = u.v8;
                __syncthreads();
            }
        }
        __syncthreads();
        {   // drain d-half 1
            int T2 = tid >> 7, rr = tid & 127;
            int hl2 = rr >> 2, dseg = rr & 3;
            float f[8];
#pragma unroll
            for (int jj = 0; jj < 8; ++jj) f[jj] = tile[T2][dseg * 8 + jj][hl2];
            union { short8 v8; __hip_bfloat16 hh8[8]; } u;
#pragma unroll
            for (int jj = 0; jj < 8; ++jj) u.hh8[jj] = __float2bfloat16(f[jj]);
            int h = h0 + T2 * 32 + hl2;
            ((short8*)(w1t + (long)e * H_DIM * D_PAD + (long)h * D_PAD + d0 + 32))[dseg] = u.v8;
        }
        return;
    }

    if (bx == GATING_BLOCKS) {   // zero the padding row of xbf
        short8* xrow = (short8*)(xbf + (long)B_ROWS * D_PAD);
        if (tid < 152) xrow[tid] = (short8){0, 0, 0, 0, 0, 0, 0, 0};
        return;
    }

    // ---- gating part ----
    if (tid < N_EXP) lcnt[tid] = 0;
    if (tid < 16) y[bx * 16 + tid] = 0.f;
    __syncthreads();

    int widx = tid >> 6;
    int lane = tid & 63;
    int rowbase = bx * 16 + widx * 4;
    const float* xw = x + (long)rowbase * D_IN;

    float acc[4][8];
#pragma unroll
    for (int r = 0; r < 4; ++r)
#pragma unroll
        for (int e = 0; e < N_EXP; ++e) acc[r][e] = 0.f;

    for (int i = lane; i < 304; i += 64) {
        if (i < 300) {
            const float4* wv4 = (const float4*)(wg + (long)i * 32);
            float4 w0 = wv4[0], w1v = wv4[1], w2 = wv4[2], w3 = wv4[3],
                   w4 = wv4[4], w5 = wv4[5], w6 = wv4[6], w7 = wv4[7];
#pragma unroll
            for (int r = 0; r < 4; ++r) {
                float4 xv = ((const float4*)(xw + (long)r * D_IN))[i];
                acc[r][0] += xv.x * w0.x + xv.y * w2.x + xv.z * w4.x + xv.w * w6.x;
                acc[r][1] += xv.x * w0.y + xv.y * w2.y + xv.z * w4.y + xv.w * w6.y;
                acc[r][2] += xv.x * w0.z + xv.y * w2.z + xv.z * w4.z + xv.w * w6.z;
                acc[r][3] += xv.x * w0.w + xv.y * w2.w + xv.z * w4.w + xv.w * w6.w;
                acc[r][4] += xv.x * w1v.x + xv.y * w3.x + xv.z * w5.x + xv.w * w7.x;
                acc[r][5] += xv.x * w1v.y + xv.y * w3.y + xv.z * w5.y + xv.w * w7.y;
                acc[r][6] += xv.x * w1v.z + xv.y * w3.z + xv.z * w5.z + xv.w * w7.z;
                acc[r][7] += xv.x * w1v.w + xv.y * w3.w + xv.z * w5.w + xv.w * w7.w;
                ((short4v*)(xbf + (long)(rowbase + r) * D_PAD))[i] = pack_bf16x4(xv);
            }
        } else {
#pragma unroll
            for (int r = 0; r < 4; ++r)
                ((short4v*)(xbf + (long)(rowbase + r) * D_PAD))[i] = (short4v){0, 0, 0, 0};
        }
    }

#pragma unroll
    for (int r = 0; r < 4; ++r)
#pragma unroll
        for (int e = 0; e < N_EXP; ++e) {
            float v = acc[r][e];
#pragma unroll
            for (int off = 32; off > 0; off >>= 1) v += __shfl_xor(v, off, 64);
            acc[r][e] = v;
        }

    float my[N_EXP];
#pragma unroll
    for (int e = 0; e < N_EXP; ++e) my[e] = acc[0][e];
#pragma unroll
    for (int r = 1; r < 4; ++r)
#pragma unroll
        for (int e = 0; e < N_EXP; ++e)
            if (lane == r) my[e] = acc[r][e];

    int i0 = 0, i1 = 1, s0 = 0, s1 = 0;
    float g0 = 0.f, g1 = 0.f;
    if (lane < 4) {
        float m = my[0];
#pragma unroll
        for (int e = 1; e < N_EXP; ++e) m = fmaxf(m, my[e]);
        float p[N_EXP], s = 0.f;
#pragma unroll
        for (int e = 0; e < N_EXP; ++e) { p[e] = expf(my[e] - m); s += p[e]; }
#pragma unroll
        for (int e = 1; e < N_EXP; ++e) if (p[e] > p[i0]) i0 = e;
        i1 = (i0 == 0) ? 1 : 0;
#pragma unroll
        for (int e = 0; e < N_EXP; ++e) if (e != i0 && p[e] > p[i1]) i1 = e;
        float v0 = p[i0] / s, v1 = p[i1] / s;
        float inv = 1.f / (v0 + v1 + GATE_EPS);
        g0 = v0 * inv; g1 = v1 * inv;
        s0 = atomicAdd(&lcnt[i0], 1);
        s1 = atomicAdd(&lcnt[i1], 1);
    }
    __syncthreads();
    if (tid < N_EXP) base[tid] = atomicAdd(&cnt[tid * CNT_STRIDE], lcnt[tid]);
    __syncthreads();
    if (lane < 4) {
        int row = rowbase + lane;
        int p0 = i0 * R_CAP + base[i0] + s0;
        pairRowC[p0] = row; pairGateC[p0] = g0;
        int p1 = i1 * R_CAP + base[i1] + s1;
        pairRowC[p1] = row; pairGateC[p1] = g1;
    }
}

// ---------------- 2. expert GEMM (128x128, BK=32, XCD==expert, A-DIRECT) ----------------
// Round-0 2-barrier structure (verified 109us; compiler schedules it best) with the
// A-side LDS round-trip removed: the MFMA A-fragment is exactly a contiguous 16B
// global read at xbf[ridx[l&15]]*D_PAD + kt*32 + quad*8 (seg-swizzle algebra cancels:
// read-side qsw ^ ((l15>>1)&3) == quad). A rows are wave-private and L2-hot (row-tile
// 311KB + B 2.4MB < 4MB per-XCD L2), so global beats staging. Per K-step:
// 2 global_load_lds + 4 global_dwordx4 + 4 ds_read + 16 MFMA (was 4 gll + 8 ds_read).
__global__ __launch_bounds__(256) void gemm_kernel(
    const __hip_bfloat16* __restrict__ xbf, const __hip_bfloat16* __restrict__ w1t,
    const float* __restrict__ b1, const int* __restrict__ cnt,
    const int* __restrict__ pairRowC,
    __hip_bfloat16* __restrict__ hbuf)
{
    // bi&7 = XCD (dispatch round-robin) = expert: XCD k owns row-tiles
    // [36k, 36k+36) == expert k's region; its 2.4 MB B stays L2-resident.
    int bi = blockIdx.x;
    int xcd = bi & 7;
    int j = bi >> 3;                 // [0, 288)
    int col0 = (j & 7) << 7;
    int rt = xcd * 36 + (j >> 3);    // [0, 288)
    int row0 = rt << 7;
    int e = xcd;                     // rt/36 == xcd by construction
    int cnt_e = cnt[e * CNT_STRIDE];
    if (row0 - e * R_CAP >= cnt_e) return;   // fully-padded tile

    __shared__ short lB[128 * 32];   // 8 KB, seg XOR-swizzled by (row>>1)&3

    int t = threadIdx.x;
    int lane = t & 63, w = t >> 6;
    int wm = (w >> 1) * 64, wn = (w & 1) * 64;
    int l15 = lane & 15, quad = lane >> 4;
    int qsw = quad ^ ((l15 >> 1) & 3);

    f32x4 acc[4][4];
#pragma unroll
    for (int i = 0; i < 4; ++i)
#pragma unroll
        for (int j2 = 0; j2 < 4; ++j2) acc[i][j2] = (f32x4){0.f, 0.f, 0.f, 0.f};

    // A-direct row pointers: lane l needs rows wm + i*16 + (l&15), k-slice quad*8
    const __hip_bfloat16* Aptr[4];
#pragma unroll
    for (int i = 0; i < 4; ++i) {
        int ridx = pairRowC[row0 + wm + i * 16 + l15];
        // pad slots hold 0xAA poison -> clamp to the zero row of xbf
        ridx = ((unsigned)ridx > B_ROWS) ? B_ROWS : ridx;
        Aptr[i] = xbf + (long)ridx * D_PAD + quad * 8;
    }

    // B staging: thread t stages rows r1=t>>2 and r1+64, 16B seg (t&3), XOR-swizzled src
    int r1 = t >> 2, seg = t & 3;
    int sw = seg ^ ((r1 >> 1) & 3);
    const __hip_bfloat16* Bb = w1t + (long)e * H_DIM * D_PAD + (long)col0 * D_PAD;
    const __hip_bfloat16* Brow1 = Bb + (long)r1 * D_PAD + sw * 8;
    const __hip_bfloat16* Brow2 = Bb + (long)(r1 + 64) * D_PAD + sw * 8;
    char* lBc = (char*)lB;

    for (int kt = 0; kt < NT; ++kt) {
        int k0 = kt * 32;
        __syncthreads();
        load_lds16(Brow1 + k0, lBc + t * 16);
        load_lds16(Brow2 + k0, lBc + t * 16 + 4096);
        bf16x8 af[4];
#pragma unroll
        for (int i = 0; i < 4; ++i)
            af[i] = *(const bf16x8*)(Aptr[i] + k0);
        __syncthreads();   // drains B staging + af loads together

        bf16x8 bfr[4];
#pragma unroll
        for (int j2 = 0; j2 < 4; ++j2)
            bfr[j2] = *(const bf16x8*)(lBc + (wn + j2 * 16 + l15) * 64 + qsw * 16);
#pragma unroll
        for (int i = 0; i < 4; ++i)
#pragma unroll
            for (int j2 = 0; j2 < 4; ++j2)
                acc[i][j2] = __builtin_amdgcn_mfma_f32_16x16x32_bf16(af[i], bfr[j2], acc[i][j2], 0, 0, 0);
    }

    // epilogue: bias + bf16 store (C/D layout: col = lane&15, row = quad*4 + r)
#pragma unroll
    for (int i = 0; i < 4; ++i) {
        int lr = wm + i * 16 + quad * 4;
#pragma unroll
        for (int j2 = 0; j2 < 4; ++j2) {
            int gc = col0 + wn + j2 * 16 + l15;
            float bias = b1[e * H_DIM + gc];
#pragma unroll
            for (int r = 0; r < 4; ++r) {
                float v = acc[i][j2][r] + bias;
                hbuf[(long)(row0 + lr + r) * H_DIM + gc] = __float2bfloat16(v);
            }
        }
    }
}

// ---------------- 3. LN + ReLU + head + sigmoid + combine (wave-per-row) ----------------
__global__ __launch_bounds__(256) void ln_head_kernel(
    const __hip_bfloat16* __restrict__ hbuf, const int* __restrict__ cnt,
    const int* __restrict__ pairRowC, const float* __restrict__ pairGateC,
    const float* __restrict__ g1, const float* __restrict__ be1,
    const float* __restrict__ W2, const float* __restrict__ b2,
    float* __restrict__ y)
{
    int tid = threadIdx.x;
    int p = blockIdx.x * 4 + (tid >> 6);
    int e = p / R_CAP;
    int slot = p - e * R_CAP;
    if (slot >= cnt[e * CNT_STRIDE]) return;   // padding slot (incl. poisoned)

    int lane = tid & 63;
    int row = pairRowC[p];
    float gate = pairGateC[p];
    const short4v* hr = (const short4v*)(hbuf + (long)p * H_DIM);

    float v[16];
    float sum = 0.f, sumsq = 0.f;
#pragma unroll
    for (int k = 0; k < 4; ++k) {
        union { short4v s; __hip_bfloat16 h[4]; } hv;
        hv.s = hr[lane + k * 64];
#pragma unroll
        for (int j = 0; j < 4; ++j) {
            float f = __bfloat162float(hv.h[j]);
            v[k * 4 + j] = f;
            sum += f;
            sumsq += f * f;
        }
    }
#pragma unroll
    for (int off = 32; off > 0; off >>= 1) {
        sum += __shfl_xor(sum, off, 64);
        sumsq += __shfl_xor(sumsq, off, 64);
    }
    float mu = sum * (1.f / H_DIM);
    float var = sumsq * (1.f / H_DIM) - mu * mu;
    float rstd = rsqrtf(var + LN_EPS);

    float z = 0.f;
#pragma unroll
    for (int k = 0; k < 4; ++k) {
        float4 gv = ((const float4*)(g1 + e * H_DIM))[lane + k * 64];
        float4 bv = ((const float4*)(be1 + e * H_DIM))[lane + k * 64];
        float4 wv = ((const float4*)(W2 + e * H_DIM))[lane + k * 64];
        z += fmaxf((v[k*4+0] - mu) * rstd * gv.x + bv.x, 0.f) * wv.x;
        z += fmaxf((v[k*4+1] - mu) * rstd * gv.y + bv.y, 0.f) * wv.y;
        z += fmaxf((v[k*4+2] - mu) * rstd * gv.z + bv.z, 0.f) * wv.z;
        z += fmaxf((v[k*4+3] - mu) * rstd * gv.w + bv.w, 0.f) * wv.w;
    }
#pragma unroll
    for (int off = 32; off > 0; off >>= 1) z += __shfl_xor(z, off, 64);
    if (lane == 0) {
        float zt = z + b2[e];
        float o = 1.f / (1.f + expf(-zt));
        atomicAdd(&y[row], gate * o);
    }
}

extern "C" void kernel_launch(void* const* d_in, const int* in_sizes, int n_in,
                              void* d_out, int out_size, void* d_ws, size_t ws_size,
                              hipStream_t stream)
{
    const float* x   = (const float*)d_in[0];
    const float* wg  = (const float*)d_in[1];
    const float* W1  = (const float*)d_in[2];
    const float* b1  = (const float*)d_in[3];
    const float* g1  = (const float*)d_in[4];
    const float* be1 = (const float*)d_in[5];
    const float* W2  = (const float*)d_in[6];
    const float* b2  = (const float*)d_in[7];
    float* y = (float*)d_out;

    char* ws = (char*)d_ws;
    int*   cnt       = (int*)(ws + O_CNT);
    int*   pairRowC  = (int*)(ws + O_PROWC);
    float* pairGateC = (float*)(ws + O_PGATEC);
    __hip_bfloat16* xbf  = (__hip_bfloat16*)(ws + O_XBF);
    __hip_bfloat16* w1t  = (__hip_bfloat16*)(ws + O_W1T);
    __hip_bfloat16* hbuf = (__hip_bfloat16*)(ws + O_HBUF);

    hipMemsetAsync(cnt, 0, 512, stream);

    prep_kernel<<<PREP_BLOCKS, 256, 0, stream>>>(x, wg, cnt, pairRowC, pairGateC,
                                                 xbf, y, W1, w1t);
    gemm_kernel<<<N_RT * 8, 256, 0, stream>>>(xbf, w1t, b1, cnt, pairRowC, hbuf);
    ln_head_kernel<<<CAP / 4, 256, 0, stream>>>(hbuf, cnt, pairRowC, pairGateC,
                                                g1, be1, W2, b2, y);
}

// Round 5
// 310.399 us; speedup vs baseline: 1.2313x; 1.2313x over previous
//
#include <hip/hip_runtime.h>
#include <hip/hip_bf16.h>
#include <stdint.h>

#define B_ROWS 16384
#define D_IN   1200
#define D_PAD  1216      // 19 * 64
#define N_EXP  8
#define H_DIM  1024
#define R_CAP  4608      // fixed per-expert region (counts ~4096 +- 55; 9 sigma margin)
#define CAP    36864     // 8 * R_CAP
#define N_RT   288       // CAP / 128 row-tiles (36 per expert/XCD)
#define LN_EPS 1e-5f
#define GATE_EPS 1e-6f
#define CNT_STRIDE 16    // pad expert counters to separate 64B cache lines

// ---- workspace layout (bytes) ----
#define O_CNT    0           // 512 B
#define O_PROWC  512         // 36864 ints  -> 147968
#define O_PGATEC 147968      // 36864 floats -> 295424
#define O_XBF    295424      // 16385*1216*2 -> 40143744 (row 16384 = zeros)
#define O_W1T    40143744    // 8*1024*1216*2 -> 60066688
#define O_HBUF   60066688    // 36864*1024*2 -> 135564160 (~130 MB total)

#define GATING_BLOCKS (B_ROWS / 16)       // 1024 (4 rows/wave, 4 waves)
#define W1T_BLOCKS    (19 * 16 * 8)       // 2432  (64d x 64h tiles)
#define PREP_BLOCKS   (GATING_BLOCKS + 1 + W1T_BLOCKS)   // 3457

#define NT64      (D_PAD / 64)            // 19 K-tiles of 64

typedef short bf16x8 __attribute__((ext_vector_type(8)));
typedef short short8 __attribute__((ext_vector_type(8)));
typedef short short4v __attribute__((ext_vector_type(4)));
typedef float f32x4 __attribute__((ext_vector_type(4)));

__device__ __forceinline__ void load_lds16(const void* gptr, void* ldsptr) {
    __builtin_amdgcn_global_load_lds(
        (__attribute__((address_space(1))) void*)const_cast<void*>(gptr),
        (__attribute__((address_space(3))) void*)ldsptr, 16, 0, 0);
}

__device__ __forceinline__ short4v pack_bf16x4(float4 a) {
    union { short4v v; __hip_bfloat16 h[4]; } u;
    u.h[0] = __float2bfloat16(a.x); u.h[1] = __float2bfloat16(a.y);
    u.h[2] = __float2bfloat16(a.z); u.h[3] = __float2bfloat16(a.w);
    return u.v;
}

// ---------------- 1. prep: gating (blocks 0..1024) + W1 transpose (blocks 1025..) ----------------
// gating and w1t are independent; merging lets the BW-light transpose overlap the
// BW-heavy gating instead of serializing, and saves a launch gap.  (verified ~11us, R2)
__global__ __launch_bounds__(256) void prep_kernel(
    const float* __restrict__ x, const float* __restrict__ wg,
    int* __restrict__ cnt, int* __restrict__ pairRowC, float* __restrict__ pairGateC,
    __hip_bfloat16* __restrict__ xbf, float* __restrict__ y,
    const float* __restrict__ W1, __hip_bfloat16* __restrict__ w1t)
{
    __shared__ int lcnt[N_EXP];
    __shared__ int base[N_EXP];
    __shared__ float tile[2][32][33];
    int bx = blockIdx.x;
    int tid = threadIdx.x;

    if (bx > GATING_BLOCKS) {
        // ---- w1t part: W1 [E][D][H] fp32 -> w1t [E][H][D_PAD] bf16 ----
        int b = bx - GATING_BLOCKS - 1;        // [0, 2432)
        int d0 = (b % 19) * 64;
        int h0 = ((b / 19) % 16) * 64;
        int e = b / (19 * 16);
        const float* src = W1 + (long)e * D_IN * H_DIM;

        int hs = tid & 15;
        int dr = tid >> 4;
#pragma unroll
        for (int s = 0; s < 4; ++s) {
            int dl = dr + 16 * s;    // 0..63
            int d = d0 + dl;
            float4 v = (d < D_IN)
                ? ((const float4*)(src + (long)d * H_DIM + h0))[hs]
                : (float4){0.f, 0.f, 0.f, 0.f};
            int drl = dl & 31;
            int hl = hs * 4;
            int Th = hl >> 5;
            int hh = hl & 31;
            tile[Th][drl][hh + 0] = v.x;
            tile[Th][drl][hh + 1] = v.y;
            tile[Th][drl][hh + 2] = v.z;
            tile[Th][drl][hh + 3] = v.w;
            if (s == 1) {            // drain d-half 0
                __syncthreads();
                int T2 = tid >> 7, rr = tid & 127;
                int hl2 = rr >> 2, dseg = rr & 3;
                float f[8];
#pragma unroll
                for (int jj = 0; jj < 8; ++jj) f[jj] = tile[T2][dseg * 8 + jj][hl2];
                union { short8 v8; __hip_bfloat16 hh8[8]; } u;
#pragma unroll
                for (int jj = 0; jj < 8; ++jj) u.hh8[jj] = __float2bfloat16(f[jj]);
                int h = h0 + T2 * 32 + hl2;
                ((short8*)(w1t + (long)e * H_DIM * D_PAD + (long)h * D_PAD + d0))[dseg] = u.v8;
                __syncthreads();
            }
        }
        __syncthreads();
        {   // drain d-half 1
            int T2 = tid >> 7, rr = tid & 127;
            int hl2 = rr >> 2, dseg = rr & 3;
            float f[8];
#pragma unroll
            for (int jj = 0; jj < 8; ++jj) f[jj] = tile[T2][dseg * 8 + jj][hl2];
            union { short8 v8; __hip_bfloat16 hh8[8]; } u;
#pragma unroll
            for (int jj = 0; jj < 8; ++jj) u.hh8[jj] = __float2bfloat16(f[jj]);
            int h = h0 + T2 * 32 + hl2;
            ((short8*)(w1t + (long)e * H_DIM * D_PAD + (long)h * D_PAD + d0 + 32))[dseg] = u.v8;
        }
        return;
    }

    if (bx == GATING_BLOCKS) {   // zero the padding row of xbf
        short8* xrow = (short8*)(xbf + (long)B_ROWS * D_PAD);
        if (tid < 152) xrow[tid] = (short8){0, 0, 0, 0, 0, 0, 0, 0};
        return;
    }

    // ---- gating part ----
    if (tid < N_EXP) lcnt[tid] = 0;
    if (tid < 16) y[bx * 16 + tid] = 0.f;
    __syncthreads();

    int widx = tid >> 6;
    int lane = tid & 63;
    int rowbase = bx * 16 + widx * 4;
    const float* xw = x + (long)rowbase * D_IN;

    float acc[4][8];
#pragma unroll
    for (int r = 0; r < 4; ++r)
#pragma unroll
        for (int e = 0; e < N_EXP; ++e) acc[r][e] = 0.f;

    for (int i = lane; i < 304; i += 64) {
        if (i < 300) {
            const float4* wv4 = (const float4*)(wg + (long)i * 32);
            float4 w0 = wv4[0], w1v = wv4[1], w2 = wv4[2], w3 = wv4[3],
                   w4 = wv4[4], w5 = wv4[5], w6 = wv4[6], w7 = wv4[7];
#pragma unroll
            for (int r = 0; r < 4; ++r) {
                float4 xv = ((const float4*)(xw + (long)r * D_IN))[i];
                acc[r][0] += xv.x * w0.x + xv.y * w2.x + xv.z * w4.x + xv.w * w6.x;
                acc[r][1] += xv.x * w0.y + xv.y * w2.y + xv.z * w4.y + xv.w * w6.y;
                acc[r][2] += xv.x * w0.z + xv.y * w2.z + xv.z * w4.z + xv.w * w6.z;
                acc[r][3] += xv.x * w0.w + xv.y * w2.w + xv.z * w4.w + xv.w * w6.w;
                acc[r][4] += xv.x * w1v.x + xv.y * w3.x + xv.z * w5.x + xv.w * w7.x;
                acc[r][5] += xv.x * w1v.y + xv.y * w3.y + xv.z * w5.y + xv.w * w7.y;
                acc[r][6] += xv.x * w1v.z + xv.y * w3.z + xv.z * w5.z + xv.w * w7.z;
                acc[r][7] += xv.x * w1v.w + xv.y * w3.w + xv.z * w5.w + xv.w * w7.w;
                ((short4v*)(xbf + (long)(rowbase + r) * D_PAD))[i] = pack_bf16x4(xv);
            }
        } else {
#pragma unroll
            for (int r = 0; r < 4; ++r)
                ((short4v*)(xbf + (long)(rowbase + r) * D_PAD))[i] = (short4v){0, 0, 0, 0};
        }
    }

#pragma unroll
    for (int r = 0; r < 4; ++r)
#pragma unroll
        for (int e = 0; e < N_EXP; ++e) {
            float v = acc[r][e];
#pragma unroll
            for (int off = 32; off > 0; off >>= 1) v += __shfl_xor(v, off, 64);
            acc[r][e] = v;
        }

    float my[N_EXP];
#pragma unroll
    for (int e = 0; e < N_EXP; ++e) my[e] = acc[0][e];
#pragma unroll
    for (int r = 1; r < 4; ++r)
#pragma unroll
        for (int e = 0; e < N_EXP; ++e)
            if (lane == r) my[e] = acc[r][e];

    int i0 = 0, i1 = 1, s0 = 0, s1 = 0;
    float g0 = 0.f, g1 = 0.f;
    if (lane < 4) {
        float m = my[0];
#pragma unroll
        for (int e = 1; e < N_EXP; ++e) m = fmaxf(m, my[e]);
        float p[N_EXP], s = 0.f;
#pragma unroll
        for (int e = 0; e < N_EXP; ++e) { p[e] = expf(my[e] - m); s += p[e]; }
#pragma unroll
        for (int e = 1; e < N_EXP; ++e) if (p[e] > p[i0]) i0 = e;
        i1 = (i0 == 0) ? 1 : 0;
#pragma unroll
        for (int e = 0; e < N_EXP; ++e) if (e != i0 && p[e] > p[i1]) i1 = e;
        float v0 = p[i0] / s, v1 = p[i1] / s;
        float inv = 1.f / (v0 + v1 + GATE_EPS);
        g0 = v0 * inv; g1 = v1 * inv;
        s0 = atomicAdd(&lcnt[i0], 1);
        s1 = atomicAdd(&lcnt[i1], 1);
    }
    __syncthreads();
    if (tid < N_EXP) base[tid] = atomicAdd(&cnt[tid * CNT_STRIDE], lcnt[tid]);
    __syncthreads();
    if (lane < 4) {
        int row = rowbase + lane;
        int p0 = i0 * R_CAP + base[i0] + s0;
        pairRowC[p0] = row; pairGateC[p0] = g0;
        int p1 = i1 * R_CAP + base[i1] + s1;
        pairRowC[p1] = row; pairGateC[p1] = g1;
    }
}

// ---------------- 2. expert GEMM (128x128, BK=64, XCD==expert, indirect clamped A) ----------------
// R0's verified 2-barrier structure with BK doubled 32 -> 64: the per-K-step full
// drain (__syncthreads => vmcnt(0) lgkmcnt(0), the known ~20% stall) is paid 19x
// instead of 38x. LDS 32 KB (safe vs m132's 64KB occupancy cliff).
//
// STAGING CONTRACT (fixed from R4's failure): global_load_lds writes LDS at
// wave-uniform base + lane*16 ONLY. So the LDS dest must be linear in t:
// instruction i writes bytes [i*4096 + t*16) => row (32i + (t>>3)), seg (t&7).
// All permutation lives on the GLOBAL source side (legal, per-lane addresses):
// source seg = (t&7) ^ ((t>>3)&7)  [row&7 invariant across i since 32%8==0].
// Net LDS content: lds[row][s] = global[row][s ^ (row&7)] -- the G4 XOR swizzle.
// Read side: seg (ks*4+quad) of row (.. + l15) is at lds seg (ks*4+quad)^(l15&7).
// Bank spread per ds_read_b128: each 4-bank seg group gets exactly 8 lanes = the
// even 256-access/32-bank minimum => ~0 conflicts expected (R0 pattern measured 0).
__global__ __launch_bounds__(256) void gemm_kernel(
    const __hip_bfloat16* __restrict__ xbf, const __hip_bfloat16* __restrict__ w1t,
    const float* __restrict__ b1, const int* __restrict__ cnt,
    const int* __restrict__ pairRowC,
    __hip_bfloat16* __restrict__ hbuf)
{
    // bi&7 = XCD (dispatch round-robin) = expert: XCD k owns row-tiles
    // [36k, 36k+36) == expert k's region; its 2.4 MB B stays L2-resident.
    int bi = blockIdx.x;
    int xcd = bi & 7;
    int j = bi >> 3;                 // [0, 288)
    int col0 = (j & 7) << 7;
    int rt = xcd * 36 + (j >> 3);    // [0, 288)
    int row0 = rt << 7;
    int e = xcd;                     // rt/36 == xcd by construction
    int cnt_e = cnt[e * CNT_STRIDE];
    if (row0 - e * R_CAP >= cnt_e) return;   // fully-padded tile

    __shared__ short lA[128 * 64];   // 16 KB
    __shared__ short lB[128 * 64];   // 16 KB

    int t = threadIdx.x;
    int lane = t & 63, w = t >> 6;
    int wm = (w >> 1) * 64, wn = (w & 1) * 64;
    int l15 = lane & 15, quad = lane >> 4;
    int rkey = l15 & 7;              // read-side XOR key (seg units)

    f32x4 acc[4][4];
#pragma unroll
    for (int i = 0; i < 4; ++i)
#pragma unroll
        for (int j2 = 0; j2 < 4; ++j2) acc[i][j2] = (f32x4){0.f, 0.f, 0.f, 0.f};

    // staging source pointers: instruction i covers row (32i + t>>3), seg (t&7),
    // swizzled source seg = (t&7) ^ ((t>>3)&7), in bf16 elems: *8
    int srow = t >> 3;                       // 0..31
    int soffB = ((t & 7) ^ (srow & 7)) * 8;  // bf16 elems within the 64-elem K-tile
    const __hip_bfloat16* Asrc[4];
    const __hip_bfloat16* Bsrc[4];
#pragma unroll
    for (int i = 0; i < 4; ++i) {
        int rr = srow + 32 * i;
        int ridx = pairRowC[row0 + rr];
        // pad slots hold 0xAA poison -> clamp to the zero row of xbf
        ridx = ((unsigned)ridx > B_ROWS) ? B_ROWS : ridx;
        Asrc[i] = xbf + (long)ridx * D_PAD + soffB;
        Bsrc[i] = w1t + (long)e * H_DIM * D_PAD + (long)(col0 + rr) * D_PAD + soffB;
    }
    char* lAc = (char*)lA;
    char* lBc = (char*)lB;

    for (int kt = 0; kt < NT64; ++kt) {
        int k0 = kt * 64;
        __syncthreads();
#pragma unroll
        for (int i = 0; i < 4; ++i) {
            load_lds16(Asrc[i] + k0, lAc + i * 4096 + t * 16);
            load_lds16(Bsrc[i] + k0, lBc + i * 4096 + t * 16);
        }
        __syncthreads();   // drains all 8 staging loads

#pragma unroll
        for (int ks = 0; ks < 2; ++ks) {
            int soff = ((((ks << 2) | quad)) ^ rkey) << 4;   // swizzled 16B seg, bytes
            bf16x8 af[4], bfr[4];
#pragma unroll
            for (int i = 0; i < 4; ++i)
                af[i] = *(const bf16x8*)(lAc + (wm + i * 16 + l15) * 128 + soff);
#pragma unroll
            for (int j2 = 0; j2 < 4; ++j2)
                bfr[j2] = *(const bf16x8*)(lBc + (wn + j2 * 16 + l15) * 128 + soff);
#pragma unroll
            for (int i = 0; i < 4; ++i)
#pragma unroll
                for (int j2 = 0; j2 < 4; ++j2)
                    acc[i][j2] = __builtin_amdgcn_mfma_f32_16x16x32_bf16(af[i], bfr[j2], acc[i][j2], 0, 0, 0);
        }
    }

    // epilogue: bias + bf16 store (C/D layout: col = lane&15, row = quad*4 + r)
#pragma unroll
    for (int i = 0; i < 4; ++i) {
        int lr = wm + i * 16 + quad * 4;
#pragma unroll
        for (int j2 = 0; j2 < 4; ++j2) {
            int gc = col0 + wn + j2 * 16 + l15;
            float bias = b1[e * H_DIM + gc];
#pragma unroll
            for (int rr = 0; rr < 4; ++rr) {
                float v = acc[i][j2][rr] + bias;
                hbuf[(long)(row0 + lr + rr) * H_DIM + gc] = __float2bfloat16(v);
            }
        }
    }
}

// ---------------- 3. LN + ReLU + head + sigmoid + combine (wave-per-row) ----------------
__global__ __launch_bounds__(256) void ln_head_kernel(
    const __hip_bfloat16* __restrict__ hbuf, const int* __restrict__ cnt,
    const int* __restrict__ pairRowC, const float* __restrict__ pairGateC,
    const float* __restrict__ g1, const float* __restrict__ be1,
    const float* __restrict__ W2, const float* __restrict__ b2,
    float* __restrict__ y)
{
    int tid = threadIdx.x;
    int p = blockIdx.x * 4 + (tid >> 6);
    int e = p / R_CAP;
    int slot = p - e * R_CAP;
    if (slot >= cnt[e * CNT_STRIDE]) return;   // padding slot (incl. poisoned)

    int lane = tid & 63;
    int row = pairRowC[p];
    float gate = pairGateC[p];
    const short4v* hr = (const short4v*)(hbuf + (long)p * H_DIM);

    float v[16];
    float sum = 0.f, sumsq = 0.f;
#pragma unroll
    for (int k = 0; k < 4; ++k) {
        union { short4v s; __hip_bfloat16 h[4]; } hv;
        hv.s = hr[lane + k * 64];
#pragma unroll
        for (int j = 0; j < 4; ++j) {
            float f = __bfloat162float(hv.h[j]);
            v[k * 4 + j] = f;
            sum += f;
            sumsq += f * f;
        }
    }
#pragma unroll
    for (int off = 32; off > 0; off >>= 1) {
        sum += __shfl_xor(sum, off, 64);
        sumsq += __shfl_xor(sumsq, off, 64);
    }
    float mu = sum * (1.f / H_DIM);
    float var = sumsq * (1.f / H_DIM) - mu * mu;
    float rstd = rsqrtf(var + LN_EPS);

    float z = 0.f;
#pragma unroll
    for (int k = 0; k < 4; ++k) {
        float4 gv = ((const float4*)(g1 + e * H_DIM))[lane + k * 64];
        float4 bv = ((const float4*)(be1 + e * H_DIM))[lane + k * 64];
        float4 wv = ((const float4*)(W2 + e * H_DIM))[lane + k * 64];
        z += fmaxf((v[k*4+0] - mu) * rstd * gv.x + bv.x, 0.f) * wv.x;
        z += fmaxf((v[k*4+1] - mu) * rstd * gv.y + bv.y, 0.f) * wv.y;
        z += fmaxf((v[k*4+2] - mu) * rstd * gv.z + bv.z, 0.f) * wv.z;
        z += fmaxf((v[k*4+3] - mu) * rstd * gv.w + bv.w, 0.f) * wv.w;
    }
#pragma unroll
    for (int off = 32; off > 0; off >>= 1) z += __shfl_xor(z, off, 64);
    if (lane == 0) {
        float zt = z + b2[e];
        float o = 1.f / (1.f + expf(-zt));
        atomicAdd(&y[row], gate * o);
    }
}

extern "C" void kernel_launch(void* const* d_in, const int* in_sizes, int n_in,
                              void* d_out, int out_size, void* d_ws, size_t ws_size,
                              hipStream_t stream)
{
    const float* x   = (const float*)d_in[0];
    const float* wg  = (const float*)d_in[1];
    const float* W1  = (const float*)d_in[2];
    const float* b1  = (const float*)d_in[3];
    const float* g1  = (const float*)d_in[4];
    const float* be1 = (const float*)d_in[5];
    const float* W2  = (const float*)d_in[6];
    const float* b2  = (const float*)d_in[7];
    float* y = (float*)d_out;

    char* ws = (char*)d_ws;
    int*   cnt       = (int*)(ws + O_CNT);
    int*   pairRowC  = (int*)(ws + O_PROWC);
    float* pairGateC = (float*)(ws + O_PGATEC);
    __hip_bfloat16* xbf  = (__hip_bfloat16*)(ws + O_XBF);
    __hip_bfloat16* w1t  = (__hip_bfloat16*)(ws + O_W1T);
    __hip_bfloat16* hbuf = (__hip_bfloat16*)(ws + O_HBUF);

    hipMemsetAsync(cnt, 0, 512, stream);

    prep_kernel<<<PREP_BLOCKS, 256, 0, stream>>>(x, wg, cnt, pairRowC, pairGateC,
                                                 xbf, y, W1, w1t);
    gemm_kernel<<<N_RT * 8, 256, 0, stream>>>(xbf, w1t, b1, cnt, pairRowC, hbuf);
    ln_head_kernel<<<CAP / 4, 256, 0, stream>>>(hbuf, cnt, pairRowC, pairGateC,
                                                g1, be1, W2, b2, y);
}

// Round 6
// 293.475 us; speedup vs baseline: 1.3023x; 1.0577x over previous
//
#include <hip/hip_runtime.h>
#include <hip/hip_bf16.h>
#include <stdint.h>

#define B_ROWS 16384
#define D_IN   1200
#define D_PAD  1216      // 19 * 64
#define N_EXP  8
#define H_DIM  1024
#define R_CAP  4608      // fixed per-expert region (counts ~4096 +- 55; 9 sigma margin)
#define CAP    36864     // 8 * R_CAP
#define N_RT   288       // CAP / 128 row-tiles (36 per expert/XCD)
#define LN_EPS 1e-5f
#define GATE_EPS 1e-6f
#define CNT_STRIDE 16    // pad expert counters to separate 64B cache lines

// ---- workspace layout (bytes) ----
#define O_CNT    0           // 512 B
#define O_PROWC  512         // 36864 ints  -> 147968
#define O_PGATEC 147968      // 36864 floats -> 295424
#define O_XBF    295424      // 16385*1216*2 -> 40143744 (row 16384 = zeros)
#define O_W1T    40143744    // 8*1024*1216*2 -> 60066688
#define O_HBUF   60066688    // 36864*1024*2 -> 135564160 (~130 MB total)

#define GATING_BLOCKS (B_ROWS / 16)       // 1024 (4 rows/wave, 4 waves)
#define W1T_BLOCKS    (19 * 16 * 8)       // 2432  (64d x 64h tiles)
#define PREP_BLOCKS   (GATING_BLOCKS + 1 + W1T_BLOCKS)   // 3457

#define NT        (D_PAD / 32)            // 38 K-tiles

typedef short bf16x8 __attribute__((ext_vector_type(8)));
typedef short short8 __attribute__((ext_vector_type(8)));
typedef short short4v __attribute__((ext_vector_type(4)));
typedef float f32x4 __attribute__((ext_vector_type(4)));

__device__ __forceinline__ void load_lds16(const void* gptr, void* ldsptr) {
    __builtin_amdgcn_global_load_lds(
        (__attribute__((address_space(1))) void*)const_cast<void*>(gptr),
        (__attribute__((address_space(3))) void*)ldsptr, 16, 0, 0);
}

__device__ __forceinline__ short4v pack_bf16x4(float4 a) {
    union { short4v v; __hip_bfloat16 h[4]; } u;
    u.h[0] = __float2bfloat16(a.x); u.h[1] = __float2bfloat16(a.y);
    u.h[2] = __float2bfloat16(a.z); u.h[3] = __float2bfloat16(a.w);
    return u.v;
}

// ---------------- 1. prep: gating (blocks 0..1024) + W1 transpose (blocks 1025..) ----------------
// gating and w1t are independent; merging lets the BW-light transpose overlap the
// BW-heavy gating instead of serializing, and saves a launch gap.  (verified ~11us, R2)
__global__ __launch_bounds__(256) void prep_kernel(
    const float* __restrict__ x, const float* __restrict__ wg,
    int* __restrict__ cnt, int* __restrict__ pairRowC, float* __restrict__ pairGateC,
    __hip_bfloat16* __restrict__ xbf, float* __restrict__ y,
    const float* __restrict__ W1, __hip_bfloat16* __restrict__ w1t)
{
    __shared__ int lcnt[N_EXP];
    __shared__ int base[N_EXP];
    __shared__ float tile[2][32][33];
    int bx = blockIdx.x;
    int tid = threadIdx.x;

    if (bx > GATING_BLOCKS) {
        // ---- w1t part: W1 [E][D][H] fp32 -> w1t [E][H][D_PAD] bf16 ----
        int b = bx - GATING_BLOCKS - 1;        // [0, 2432)
        int d0 = (b % 19) * 64;
        int h0 = ((b / 19) % 16) * 64;
        int e = b / (19 * 16);
        const float* src = W1 + (long)e * D_IN * H_DIM;

        int hs = tid & 15;
        int dr = tid >> 4;
#pragma unroll
        for (int s = 0; s < 4; ++s) {
            int dl = dr + 16 * s;    // 0..63
            int d = d0 + dl;
            float4 v = (d < D_IN)
                ? ((const float4*)(src + (long)d * H_DIM + h0))[hs]
                : (float4){0.f, 0.f, 0.f, 0.f};
            int drl = dl & 31;
            int hl = hs * 4;
            int Th = hl >> 5;
            int hh = hl & 31;
            tile[Th][drl][hh + 0] = v.x;
            tile[Th][drl][hh + 1] = v.y;
            tile[Th][drl][hh + 2] = v.z;
            tile[Th][drl][hh + 3] = v.w;
            if (s == 1) {            // drain d-half 0
                __syncthreads();
                int T2 = tid >> 7, rr = tid & 127;
                int hl2 = rr >> 2, dseg = rr & 3;
                float f[8];
#pragma unroll
                for (int jj = 0; jj < 8; ++jj) f[jj] = tile[T2][dseg * 8 + jj][hl2];
                union { short8 v8; __hip_bfloat16 hh8[8]; } u;
#pragma unroll
                for (int jj = 0; jj < 8; ++jj) u.hh8[jj] = __float2bfloat16(f[jj]);
                int h = h0 + T2 * 32 + hl2;
                ((short8*)(w1t + (long)e * H_DIM * D_PAD + (long)h * D_PAD + d0))[dseg] = u.v8;
                __syncthreads();
            }
        }
        __syncthreads();
        {   // drain d-half 1
            int T2 = tid >> 7, rr = tid & 127;
            int hl2 = rr >> 2, dseg = rr & 3;
            float f[8];
#pragma unroll
            for (int jj = 0; jj < 8; ++jj) f[jj] = tile[T2][dseg * 8 + jj][hl2];
            union { short8 v8; __hip_bfloat16 hh8[8]; } u;
#pragma unroll
            for (int jj = 0; jj < 8; ++jj) u.hh8[jj] = __float2bfloat16(f[jj]);
            int h = h0 + T2 * 32 + hl2;
            ((short8*)(w1t + (long)e * H_DIM * D_PAD + (long)h * D_PAD + d0 + 32))[dseg] = u.v8;
        }
        return;
    }

    if (bx == GATING_BLOCKS) {   // zero the padding row of xbf
        short8* xrow = (short8*)(xbf + (long)B_ROWS * D_PAD);
        if (tid < 152) xrow[tid] = (short8){0, 0, 0, 0, 0, 0, 0, 0};
        return;
    }

    // ---- gating part ----
    if (tid < N_EXP) lcnt[tid] = 0;
    if (tid < 16) y[bx * 16 + tid] = 0.f;
    __syncthreads();

    int widx = tid >> 6;
    int lane = tid & 63;
    int rowbase = bx * 16 + widx * 4;
    const float* xw = x + (long)rowbase * D_IN;

    float acc[4][8];
#pragma unroll
    for (int r = 0; r < 4; ++r)
#pragma unroll
        for (int e = 0; e < N_EXP; ++e) acc[r][e] = 0.f;

    for (int i = lane; i < 304; i += 64) {
        if (i < 300) {
            const float4* wv4 = (const float4*)(wg + (long)i * 32);
            float4 w0 = wv4[0], w1v = wv4[1], w2 = wv4[2], w3 = wv4[3],
                   w4 = wv4[4], w5 = wv4[5], w6 = wv4[6], w7 = wv4[7];
#pragma unroll
            for (int r = 0; r < 4; ++r) {
                float4 xv = ((const float4*)(xw + (long)r * D_IN))[i];
                acc[r][0] += xv.x * w0.x + xv.y * w2.x + xv.z * w4.x + xv.w * w6.x;
                acc[r][1] += xv.x * w0.y + xv.y * w2.y + xv.z * w4.y + xv.w * w6.y;
                acc[r][2] += xv.x * w0.z + xv.y * w2.z + xv.z * w4.z + xv.w * w6.z;
                acc[r][3] += xv.x * w0.w + xv.y * w2.w + xv.z * w4.w + xv.w * w6.w;
                acc[r][4] += xv.x * w1v.x + xv.y * w3.x + xv.z * w5.x + xv.w * w7.x;
                acc[r][5] += xv.x * w1v.y + xv.y * w3.y + xv.z * w5.y + xv.w * w7.y;
                acc[r][6] += xv.x * w1v.z + xv.y * w3.z + xv.z * w5.z + xv.w * w7.z;
                acc[r][7] += xv.x * w1v.w + xv.y * w3.w + xv.z * w5.w + xv.w * w7.w;
                ((short4v*)(xbf + (long)(rowbase + r) * D_PAD))[i] = pack_bf16x4(xv);
            }
        } else {
#pragma unroll
            for (int r = 0; r < 4; ++r)
                ((short4v*)(xbf + (long)(rowbase + r) * D_PAD))[i] = (short4v){0, 0, 0, 0};
        }
    }

#pragma unroll
    for (int r = 0; r < 4; ++r)
#pragma unroll
        for (int e = 0; e < N_EXP; ++e) {
            float v = acc[r][e];
#pragma unroll
            for (int off = 32; off > 0; off >>= 1) v += __shfl_xor(v, off, 64);
            acc[r][e] = v;
        }

    float my[N_EXP];
#pragma unroll
    for (int e = 0; e < N_EXP; ++e) my[e] = acc[0][e];
#pragma unroll
    for (int r = 1; r < 4; ++r)
#pragma unroll
        for (int e = 0; e < N_EXP; ++e)
            if (lane == r) my[e] = acc[r][e];

    int i0 = 0, i1 = 1, s0 = 0, s1 = 0;
    float g0 = 0.f, g1 = 0.f;
    if (lane < 4) {
        float m = my[0];
#pragma unroll
        for (int e = 1; e < N_EXP; ++e) m = fmaxf(m, my[e]);
        float p[N_EXP], s = 0.f;
#pragma unroll
        for (int e = 0; e < N_EXP; ++e) { p[e] = expf(my[e] - m); s += p[e]; }
#pragma unroll
        for (int e = 1; e < N_EXP; ++e) if (p[e] > p[i0]) i0 = e;
        i1 = (i0 == 0) ? 1 : 0;
#pragma unroll
        for (int e = 0; e < N_EXP; ++e) if (e != i0 && p[e] > p[i1]) i1 = e;
        float v0 = p[i0] / s, v1 = p[i1] / s;
        float inv = 1.f / (v0 + v1 + GATE_EPS);
        g0 = v0 * inv; g1 = v1 * inv;
        s0 = atomicAdd(&lcnt[i0], 1);
        s1 = atomicAdd(&lcnt[i1], 1);
    }
    __syncthreads();
    if (tid < N_EXP) base[tid] = atomicAdd(&cnt[tid * CNT_STRIDE], lcnt[tid]);
    __syncthreads();
    if (lane < 4) {
        int row = rowbase + lane;
        int p0 = i0 * R_CAP + base[i0] + s0;
        pairRowC[p0] = row; pairGateC[p0] = g0;
        int p1 = i1 * R_CAP + base[i1] + s1;
        pairRowC[p1] = row; pairGateC[p1] = g1;
    }
}

// ---------------- 2. expert GEMM (128x128, BK=32, XCD==expert, indirect clamped A) ----------------
// R0-exact configuration, verified 109.4us / MfmaUtil 31.5 / 0 conflicts.
// Local optimum: deeper pipeline (R1), hand ring (R2), A-direct (R3), BK=64 (R5)
// all lose 15-90%. The 16KB LDS keeps ~3 blocks/CU resident; m114 wave-level
// overlap across blocks is what hides the staging drain -- do not trade it away.
__global__ __launch_bounds__(256) void gemm_kernel(
    const __hip_bfloat16* __restrict__ xbf, const __hip_bfloat16* __restrict__ w1t,
    const float* __restrict__ b1, const int* __restrict__ cnt,
    const int* __restrict__ pairRowC,
    __hip_bfloat16* __restrict__ hbuf)
{
    // bi&7 = XCD (dispatch round-robin) = expert: XCD k owns row-tiles
    // [36k, 36k+36) == expert k's region; its 2.4 MB B stays L2-resident.
    int bi = blockIdx.x;
    int xcd = bi & 7;
    int j = bi >> 3;                 // [0, 288)
    int col0 = (j & 7) << 7;
    int rt = xcd * 36 + (j >> 3);    // [0, 288)
    int row0 = rt << 7;
    int e = xcd;                     // rt/36 == xcd by construction
    int cnt_e = cnt[e * CNT_STRIDE];
    if (row0 - e * R_CAP >= cnt_e) return;   // fully-padded tile

    __shared__ short lA[128 * 32];   // seg XOR-swizzled by (row>>1)&3
    __shared__ short lB[128 * 32];

    int t = threadIdx.x;
    int lane = t & 63, w = t >> 6;
    int wm = (w >> 1) * 64, wn = (w & 1) * 64;
    int l15 = lane & 15, quad = lane >> 4;
    int qsw = quad ^ ((l15 >> 1) & 3);

    f32x4 acc[4][4];
#pragma unroll
    for (int i = 0; i < 4; ++i)
#pragma unroll
        for (int j2 = 0; j2 < 4; ++j2) acc[i][j2] = (f32x4){0.f, 0.f, 0.f, 0.f};

    int r1 = t >> 2, seg = t & 3;
    int sw = seg ^ ((r1 >> 1) & 3);
    int ridx1 = pairRowC[row0 + r1];
    int ridx2 = pairRowC[row0 + 64 + r1];
    // pad slots hold 0xAA poison -> clamp to the zero row of xbf
    ridx1 = ((unsigned)ridx1 > B_ROWS) ? B_ROWS : ridx1;
    ridx2 = ((unsigned)ridx2 > B_ROWS) ? B_ROWS : ridx2;
    const __hip_bfloat16* Arow1 = xbf + (long)ridx1 * D_PAD + sw * 8;
    const __hip_bfloat16* Arow2 = xbf + (long)ridx2 * D_PAD + sw * 8;
    const __hip_bfloat16* Bb = w1t + (long)e * H_DIM * D_PAD + (long)col0 * D_PAD;
    const __hip_bfloat16* Brow1 = Bb + (long)r1 * D_PAD + sw * 8;
    const __hip_bfloat16* Brow2 = Bb + (long)(r1 + 64) * D_PAD + sw * 8;
    char* lAc = (char*)lA;
    char* lBc = (char*)lB;

    for (int kt = 0; kt < NT; ++kt) {
        __syncthreads();
        int k0 = kt * 32;
        load_lds16(Arow1 + k0, lAc + t * 16);
        load_lds16(Arow2 + k0, lAc + t * 16 + 4096);
        load_lds16(Brow1 + k0, lBc + t * 16);
        load_lds16(Brow2 + k0, lBc + t * 16 + 4096);
        __syncthreads();

        bf16x8 af[4], bfr[4];
#pragma unroll
        for (int i = 0; i < 4; ++i)
            af[i] = *(const bf16x8*)(lAc + (wm + i * 16 + l15) * 64 + qsw * 16);
#pragma unroll
        for (int j2 = 0; j2 < 4; ++j2)
            bfr[j2] = *(const bf16x8*)(lBc + (wn + j2 * 16 + l15) * 64 + qsw * 16);
#pragma unroll
        for (int i = 0; i < 4; ++i)
#pragma unroll
            for (int j2 = 0; j2 < 4; ++j2)
                acc[i][j2] = __builtin_amdgcn_mfma_f32_16x16x32_bf16(af[i], bfr[j2], acc[i][j2], 0, 0, 0);
    }

    // epilogue: bias + bf16 store (C/D layout: col = lane&15, row = quad*4 + r)
#pragma unroll
    for (int i = 0; i < 4; ++i) {
        int lr = wm + i * 16 + quad * 4;
#pragma unroll
        for (int j2 = 0; j2 < 4; ++j2) {
            int gc = col0 + wn + j2 * 16 + l15;
            float bias = b1[e * H_DIM + gc];
#pragma unroll
            for (int r = 0; r < 4; ++r) {
                float v = acc[i][j2][r] + bias;
                hbuf[(long)(row0 + lr + r) * H_DIM + gc] = __float2bfloat16(v);
            }
        }
    }
}

// ---------------- 3. LN + ReLU + head + sigmoid + combine (wave-per-row) ----------------
__global__ __launch_bounds__(256) void ln_head_kernel(
    const __hip_bfloat16* __restrict__ hbuf, const int* __restrict__ cnt,
    const int* __restrict__ pairRowC, const float* __restrict__ pairGateC,
    const float* __restrict__ g1, const float* __restrict__ be1,
    const float* __restrict__ W2, const float* __restrict__ b2,
    float* __restrict__ y)
{
    int tid = threadIdx.x;
    int p = blockIdx.x * 4 + (tid >> 6);
    int e = p / R_CAP;
    int slot = p - e * R_CAP;
    if (slot >= cnt[e * CNT_STRIDE]) return;   // padding slot (incl. poisoned)

    int lane = tid & 63;
    int row = pairRowC[p];
    float gate = pairGateC[p];
    const short4v* hr = (const short4v*)(hbuf + (long)p * H_DIM);

    float v[16];
    float sum = 0.f, sumsq = 0.f;
#pragma unroll
    for (int k = 0; k < 4; ++k) {
        union { short4v s; __hip_bfloat16 h[4]; } hv;
        hv.s = hr[lane + k * 64];
#pragma unroll
        for (int j = 0; j < 4; ++j) {
            float f = __bfloat162float(hv.h[j]);
            v[k * 4 + j] = f;
            sum += f;
            sumsq += f * f;
        }
    }
#pragma unroll
    for (int off = 32; off > 0; off >>= 1) {
        sum += __shfl_xor(sum, off, 64);
        sumsq += __shfl_xor(sumsq, off, 64);
    }
    float mu = sum * (1.f / H_DIM);
    float var = sumsq * (1.f / H_DIM) - mu * mu;
    float rstd = rsqrtf(var + LN_EPS);

    float z = 0.f;
#pragma unroll
    for (int k = 0; k < 4; ++k) {
        float4 gv = ((const float4*)(g1 + e * H_DIM))[lane + k * 64];
        float4 bv = ((const float4*)(be1 + e * H_DIM))[lane + k * 64];
        float4 wv = ((const float4*)(W2 + e * H_DIM))[lane + k * 64];
        z += fmaxf((v[k*4+0] - mu) * rstd * gv.x + bv.x, 0.f) * wv.x;
        z += fmaxf((v[k*4+1] - mu) * rstd * gv.y + bv.y, 0.f) * wv.y;
        z += fmaxf((v[k*4+2] - mu) * rstd * gv.z + bv.z, 0.f) * wv.z;
        z += fmaxf((v[k*4+3] - mu) * rstd * gv.w + bv.w, 0.f) * wv.w;
    }
#pragma unroll
    for (int off = 32; off > 0; off >>= 1) z += __shfl_xor(z, off, 64);
    if (lane == 0) {
        float zt = z + b2[e];
        float o = 1.f / (1.f + expf(-zt));
        atomicAdd(&y[row], gate * o);
    }
}

extern "C" void kernel_launch(void* const* d_in, const int* in_sizes, int n_in,
                              void* d_out, int out_size, void* d_ws, size_t ws_size,
                              hipStream_t stream)
{
    const float* x   = (const float*)d_in[0];
    const float* wg  = (const float*)d_in[1];
    const float* W1  = (const float*)d_in[2];
    const float* b1  = (const float*)d_in[3];
    const float* g1  = (const float*)d_in[4];
    const float* be1 = (const float*)d_in[5];
    const float* W2  = (const float*)d_in[6];
    const float* b2  = (const float*)d_in[7];
    float* y = (float*)d_out;

    char* ws = (char*)d_ws;
    int*   cnt       = (int*)(ws + O_CNT);
    int*   pairRowC  = (int*)(ws + O_PROWC);
    float* pairGateC = (float*)(ws + O_PGATEC);
    __hip_bfloat16* xbf  = (__hip_bfloat16*)(ws + O_XBF);
    __hip_bfloat16* w1t  = (__hip_bfloat16*)(ws + O_W1T);
    __hip_bfloat16* hbuf = (__hip_bfloat16*)(ws + O_HBUF);

    hipMemsetAsync(cnt, 0, 512, stream);

    prep_kernel<<<PREP_BLOCKS, 256, 0, stream>>>(x, wg, cnt, pairRowC, pairGateC,
                                                 xbf, y, W1, w1t);
    gemm_kernel<<<N_RT * 8, 256, 0, stream>>>(xbf, w1t, b1, cnt, pairRowC, hbuf);
    ln_head_kernel<<<CAP / 4, 256, 0, stream>>>(hbuf, cnt, pairRowC, pairGateC,
                                                g1, be1, W2, b2, y);
}